// Round 2
// baseline (224.002 us; speedup 1.0000x reference)
//
#include <hip/hip_runtime.h>
#include <math.h>

// MaskedBalancedBCELoss — hard-negative mining via count-histogram select.
//
// R12: double TLP. R11 post-mortem: VGPR 52 -> compiler holds ~5 float4 in
// flight/wave (not the 12 written); demand BW 2.1 TB/s sits exactly at the
// Little's-law equilibrium for 16 waves/CU x ~5 loads at ~700cy latency.
// The 2-copy LDS hist bought nothing (SQ_LDS_BANK_CONFLICT bit-identical
// 942663 vs 1-copy -> DS atomics ~3.7K cy/CU, acquitted) but its 33KB LDS
// capped residency at 4 blocks/CU (16 waves). Changes:
//   * back to ONE 16.6KB LDS histogram copy -> 8 blocks/CU fit (135KB LDS)
//   * K1_BLOCKS 1024 -> 2048, __launch_bounds__(256, 8) (VGPR budget 64)
//   * hot loop otherwise identical to R11 (4-step unroll, 12 loads up front,
//     branchless single-log proc1)
// k5 unchanged. Select stays in its own kernel (R9: fusion perturbs codegen).

#define NBINS1 4096
#define K1_BLOCKS 2048

struct Ctrl {
  unsigned long long pos_cnt;
  unsigned long long neg_cnt;
  unsigned long long k;
  double pos_sum;
  unsigned B;
  unsigned k_rem;
};

#define LN2F 0.69314718055994530942f

__device__ __forceinline__ double bin_mid(unsigned b) {
  return (double)__uint_as_float((b << 19) | 0x40000u);
}

// Per-element processing. Loss value bit-identical to R10/R11 (same
// expression tree) -> same bins -> midpoint model unchanged.
__device__ __forceinline__ void proc1(float p, float g, float m,
                                      unsigned& pc, unsigned& nc,
                                      double& psum, unsigned* __restrict__ hc) {
  bool gpos = (g != 0.0f);
  bool valid = (m != 0.0f);
  bool ispos = valid && gpos;
  bool isneg = valid && !gpos;
  float x = gpos ? p : 1.0f - p;
  float loss = -fmaxf(__log2f(x) * LN2F, -100.0f);
  pc += ispos ? 1u : 0u;
  nc += isneg ? 1u : 0u;
  psum += ispos ? (double)loss : 0.0;
  if (isneg) atomicAdd(&hc[__float_as_uint(loss) >> 19], 1u);
}

// ---------------- Kernel 1: reductions + level-1 histogram -----------------
extern "C" __global__ void __launch_bounds__(256, 8)
k1_hist(const float* __restrict__ pred, const float* __restrict__ gt,
        const float* __restrict__ mask, unsigned* __restrict__ hist1,
        Ctrl* __restrict__ ctrl, int n4, int n) {
  __shared__ unsigned h[NBINS1];
  for (int i = threadIdx.x; i < NBINS1; i += blockDim.x) h[i] = 0u;
  __syncthreads();

  int wv = threadIdx.x >> 6, ln = threadIdx.x & 63;

  unsigned pc = 0, nc = 0;
  double psum = 0.0;
  const float4* p4 = (const float4*)pred;
  const float4* g4 = (const float4*)gt;
  const float4* m4 = (const float4*)mask;
  int gtid = blockIdx.x * blockDim.x + threadIdx.x;
  int S = gridDim.x * blockDim.x;

  int i = gtid;
  // main: 4 grid-stride steps per iteration, 12 loads issued up front
  for (; i + 3 * S < n4; i += 4 * S) {
    float4 pv0 = p4[i];
    float4 pv1 = p4[i + S];
    float4 pv2 = p4[i + 2 * S];
    float4 pv3 = p4[i + 3 * S];
    float4 gv0 = g4[i];
    float4 gv1 = g4[i + S];
    float4 gv2 = g4[i + 2 * S];
    float4 gv3 = g4[i + 3 * S];
    float4 mv0 = m4[i];
    float4 mv1 = m4[i + S];
    float4 mv2 = m4[i + 2 * S];
    float4 mv3 = m4[i + 3 * S];

    proc1(pv0.x, gv0.x, mv0.x, pc, nc, psum, h);
    proc1(pv0.y, gv0.y, mv0.y, pc, nc, psum, h);
    proc1(pv0.z, gv0.z, mv0.z, pc, nc, psum, h);
    proc1(pv0.w, gv0.w, mv0.w, pc, nc, psum, h);
    proc1(pv1.x, gv1.x, mv1.x, pc, nc, psum, h);
    proc1(pv1.y, gv1.y, mv1.y, pc, nc, psum, h);
    proc1(pv1.z, gv1.z, mv1.z, pc, nc, psum, h);
    proc1(pv1.w, gv1.w, mv1.w, pc, nc, psum, h);
    proc1(pv2.x, gv2.x, mv2.x, pc, nc, psum, h);
    proc1(pv2.y, gv2.y, mv2.y, pc, nc, psum, h);
    proc1(pv2.z, gv2.z, mv2.z, pc, nc, psum, h);
    proc1(pv2.w, gv2.w, mv2.w, pc, nc, psum, h);
    proc1(pv3.x, gv3.x, mv3.x, pc, nc, psum, h);
    proc1(pv3.y, gv3.y, mv3.y, pc, nc, psum, h);
    proc1(pv3.z, gv3.z, mv3.z, pc, nc, psum, h);
    proc1(pv3.w, gv3.w, mv3.w, pc, nc, psum, h);
  }
  // remainder grid-stride steps
  for (; i < n4; i += S) {
    float4 pv = p4[i], gv = g4[i], mv = m4[i];
    proc1(pv.x, gv.x, mv.x, pc, nc, psum, h);
    proc1(pv.y, gv.y, mv.y, pc, nc, psum, h);
    proc1(pv.z, gv.z, mv.z, pc, nc, psum, h);
    proc1(pv.w, gv.w, mv.w, pc, nc, psum, h);
  }
  // scalar tail (n % 4 != 0)
  for (int t = n4 * 4 + gtid; t < n; t += S) {
    proc1(pred[t], gt[t], mask[t], pc, nc, psum, h);
  }

  // block reduce pc/nc/psum
  unsigned long long pcl = pc, ncl = nc;
  for (int off = 32; off > 0; off >>= 1) {
    pcl += __shfl_down(pcl, off);
    ncl += __shfl_down(ncl, off);
    psum += __shfl_down(psum, off);
  }
  __shared__ unsigned long long spc[4], snc[4];
  __shared__ double sps[4];
  if (ln == 0) { spc[wv] = pcl; snc[wv] = ncl; sps[wv] = psum; }
  __syncthreads();   // also ensures all LDS histogram atomics are complete
  if (threadIdx.x == 0) {
    unsigned long long tp = 0, tn = 0; double ts = 0.0;
    for (int w = 0; w < 4; w++) { tp += spc[w]; tn += snc[w]; ts += sps[w]; }
    atomicAdd(&ctrl->pos_cnt, tp);
    atomicAdd(&ctrl->neg_cnt, tn);
    unsafeAtomicAdd(&ctrl->pos_sum, ts);
  }
  // flush LDS histogram to global (skip empty bins)
  for (int b = threadIdx.x; b < NBINS1; b += blockDim.x) {
    unsigned c = h[b];
    if (c) atomicAdd(&hist1[b], c);
  }
}

// ---------- Kernel 5: select + midpoint neg_sum + output (1 block) ---------
extern "C" __global__ void __launch_bounds__(256)
k5_final(const unsigned* __restrict__ hist1, Ctrl* __restrict__ ctrl,
         float* __restrict__ out) {
  const int T = 256, CH = NBINS1 / T;  // 16 bins per thread
  __shared__ unsigned long long sarr[T];
  __shared__ unsigned long long sk;
  __shared__ unsigned sB, skrem;
  __shared__ double sred[4];
  int t = threadIdx.x;
  int wv = t >> 6, ln = t & 63;

  unsigned cnt[CH];
  unsigned long long tot = 0;
  for (int j = 0; j < CH; j++) { cnt[j] = hist1[t * CH + j]; tot += cnt[j]; }
  sarr[t] = tot;
  if (t == 0) {
    sB = 0xFFFFFFFFu; skrem = 0u;
    unsigned long long pos = ctrl->pos_cnt, negtot = ctrl->neg_cnt;
    unsigned long long k = 0;
    if (pos > 0) {               // FALLBACK_NEG=0 when pos==0
      k = pos * 3ull;            // floor(pos*3.0), exact in integer
      if (k > negtot) k = negtot;
    }
    ctrl->k = k;
    sk = k;
  }
  __syncthreads();
  // inclusive suffix scan: sarr[t] = sum over threads >= t
  for (int off = 1; off < T; off <<= 1) {
    unsigned long long v = (t + off < T) ? sarr[t + off] : 0ull;
    __syncthreads();
    sarr[t] += v;
    __syncthreads();
  }
  unsigned long long k = sk;
  if (k > 0) {
    unsigned long long above = sarr[t] - tot;
    if (above < k && sarr[t] >= k) {
      unsigned long long cum = above;
      for (int j = CH - 1; j >= 0; j--) {
        if (cum + (unsigned long long)cnt[j] >= k) {
          sB = (unsigned)(t * CH + j);
          skrem = (unsigned)(k - cum);
          break;
        }
        cum += cnt[j];
      }
    }
  }
  __syncthreads();
  unsigned B = sB;

  // neg_sum (midpoint model): each thread sums its own bins above B
  double s = 0.0;
  if (B != 0xFFFFFFFFu) {
    for (int j = 0; j < CH; j++) {
      unsigned bi = (unsigned)(t * CH + j);
      if (bi > B && cnt[j]) s += (double)cnt[j] * bin_mid(bi);
    }
  }
  for (int off = 32; off > 0; off >>= 1) s += __shfl_down(s, off);
  if (ln == 0) sred[wv] = s;
  __syncthreads();
  if (t == 0) {
    double neg_sum = sred[0] + sred[1] + sred[2] + sred[3];
    if (skrem > 0 && B != 0xFFFFFFFFu)
      neg_sum += (double)skrem * bin_mid(B);
    double denom = (double)ctrl->pos_cnt + (double)k + 1e-6;
    out[0] = (float)((ctrl->pos_sum + neg_sum) / denom);
  }
}

// ---------------------------------------------------------------------------
extern "C" void kernel_launch(void* const* d_in, const int* in_sizes, int n_in,
                              void* d_out, int out_size, void* d_ws, size_t ws_size,
                              hipStream_t stream) {
  const float* pred = (const float*)d_in[0];
  const float* gt   = (const float*)d_in[1];
  const float* mask = (const float*)d_in[2];
  float* out = (float*)d_out;
  int n = in_sizes[0];
  int n4 = n / 4;
  char* ws = (char*)d_ws;

  // layout: ctrl@0 (64B), hist1@256 (16KB) -> zero first 16640 bytes
  const size_t HIST1_OFF = 256;
  const size_t ZERO_BYTES = HIST1_OFF + NBINS1 * sizeof(unsigned);   // 16640

  Ctrl* ctrl = (Ctrl*)ws;
  unsigned* hist1 = (unsigned*)(ws + HIST1_OFF);

  hipMemsetAsync(d_ws, 0, ZERO_BYTES, stream);
  k1_hist<<<K1_BLOCKS, 256, 0, stream>>>(pred, gt, mask, hist1, ctrl, n4, n);
  k5_final<<<1, 256, 0, stream>>>(hist1, ctrl, out);
}

// Round 3
// 190.980 us; speedup vs baseline: 1.1729x; 1.1729x over previous
//
#include <hip/hip_runtime.h>
#include <math.h>

// MaskedBalancedBCELoss — hard-negative mining via count-histogram select.
//
// R13: break the VGPR-MLP ceiling with global_load_lds. R10-R12 showed
// in-flight bytes pinned at ~80 loads/CU no matter how waves/VGPRs are
// traded (R11: 16 waves x ~5 loads @ VGPR52 = 75us; R12: 32 waves x ~2
// @ VGPR32 = 128us). Roofline needs ~450 16B-loads/CU in flight. Fix:
// stage pred/gt/mask direct-to-LDS (3-deep per-wave pipeline, counted
// s_waitcnt vmcnt(6), no barriers in loop), process from LDS via
// ds_read_b128. In-flight: 9 x 1KB/wave x 12 waves/CU = 108 KB/CU.
//   * sbuf[DEPTH=3][4 waves][3 arrays][64 lanes] float4 = 36 KB
//   * hist 16.4 KB -> total 53.3 KB LDS -> 3 blocks/CU, 768 blocks
//   * inline-asm vmcnt waits + sched_barrier(0) (guide rule #18, T4:
//     counted vmcnt, never 0 in steady state; epilogue drains 6->3->0)
//   * remainder (n4 % S) + scalar tail use the old direct-load path
// k5 unchanged; select stays in its own kernel (R9: fusion perturbs codegen).

#define NBINS1 4096
#define K1_BLOCKS 768
#define DEPTH 3

struct Ctrl {
  unsigned long long pos_cnt;
  unsigned long long neg_cnt;
  unsigned long long k;
  double pos_sum;
  unsigned B;
  unsigned k_rem;
};

#define LN2F 0.69314718055994530942f

__device__ __forceinline__ double bin_mid(unsigned b) {
  return (double)__uint_as_float((b << 19) | 0x40000u);
}

// Per-element processing. Loss value bit-identical to R10/R11/R12 (same
// expression tree) -> same bins -> midpoint model unchanged.
__device__ __forceinline__ void proc1(float p, float g, float m,
                                      unsigned& pc, unsigned& nc,
                                      double& psum, unsigned* __restrict__ hc) {
  bool gpos = (g != 0.0f);
  bool valid = (m != 0.0f);
  bool ispos = valid && gpos;
  bool isneg = valid && !gpos;
  float x = gpos ? p : 1.0f - p;
  float loss = -fmaxf(__log2f(x) * LN2F, -100.0f);
  pc += ispos ? 1u : 0u;
  nc += isneg ? 1u : 0u;
  psum += ispos ? (double)loss : 0.0;
  if (isneg) atomicAdd(&hc[__float_as_uint(loss) >> 19], 1u);
}

// Issue 3 direct-to-LDS loads (pred/gt/mask) for one pipeline step.
// gptr is per-lane; lds base must be wave-uniform (HW writes base+lane*16).
__device__ __forceinline__ void stage3(const float4* __restrict__ p4,
                                       const float4* __restrict__ g4,
                                       const float4* __restrict__ m4,
                                       int idx, float4* sl) {
  typedef const __attribute__((address_space(1))) void gvoid_t;
  typedef __attribute__((address_space(3))) void lvoid_t;
  __builtin_amdgcn_global_load_lds((gvoid_t*)(p4 + idx), (lvoid_t*)(sl + 0 * 64), 16, 0, 0);
  __builtin_amdgcn_global_load_lds((gvoid_t*)(g4 + idx), (lvoid_t*)(sl + 1 * 64), 16, 0, 0);
  __builtin_amdgcn_global_load_lds((gvoid_t*)(m4 + idx), (lvoid_t*)(sl + 2 * 64), 16, 0, 0);
}

__device__ __forceinline__ void proc_buf(const float4* sl, int ln,
                                         unsigned& pc, unsigned& nc,
                                         double& psum, unsigned* __restrict__ h) {
  float4 pv = sl[0 * 64 + ln];
  float4 gv = sl[1 * 64 + ln];
  float4 mv = sl[2 * 64 + ln];
  proc1(pv.x, gv.x, mv.x, pc, nc, psum, h);
  proc1(pv.y, gv.y, mv.y, pc, nc, psum, h);
  proc1(pv.z, gv.z, mv.z, pc, nc, psum, h);
  proc1(pv.w, gv.w, mv.w, pc, nc, psum, h);
}

// ---------------- Kernel 1: reductions + level-1 histogram -----------------
extern "C" __global__ void __launch_bounds__(256, 3)
k1_hist(const float* __restrict__ pred, const float* __restrict__ gt,
        const float* __restrict__ mask, unsigned* __restrict__ hist1,
        Ctrl* __restrict__ ctrl, int n4, int n) {
  __shared__ unsigned h[NBINS1];
  __shared__ float4 sbuf[DEPTH][4][3 * 64];  // 36 KB, per-wave private slices
  for (int i = threadIdx.x; i < NBINS1; i += blockDim.x) h[i] = 0u;
  __syncthreads();

  int wv = threadIdx.x >> 6, ln = threadIdx.x & 63;

  unsigned pc = 0, nc = 0;
  double psum = 0.0;
  const float4* p4 = (const float4*)pred;
  const float4* g4 = (const float4*)gt;
  const float4* m4 = (const float4*)mask;
  int gtid = blockIdx.x * blockDim.x + threadIdx.x;
  int S = gridDim.x * blockDim.x;

  int FULL = n4 / S;                       // steps with every thread in-range
  int PST = (FULL >= DEPTH) ? FULL : 0;    // pipelined steps (0 = fallback)

  if (PST) {
    // prologue: fill all DEPTH buffers
    stage3(p4, g4, m4, 0 * S + gtid, &sbuf[0][wv][0]);
    stage3(p4, g4, m4, 1 * S + gtid, &sbuf[1][wv][0]);
    stage3(p4, g4, m4, 2 * S + gtid, &sbuf[2][wv][0]);
    int buf = 0;
    // main: process oldest buffer, restage it DEPTH steps ahead.
    // vmcnt(6): 9 loads outstanding, wait until cur buffer's 3 landed.
    for (int it = 0; it < PST - DEPTH; ++it) {
      float4* sl = &sbuf[buf][wv][0];
      asm volatile("s_waitcnt vmcnt(6)" ::: "memory");
      __builtin_amdgcn_sched_barrier(0);
      proc_buf(sl, ln, pc, nc, psum, h);
      __builtin_amdgcn_sched_barrier(0);
      stage3(p4, g4, m4, (it + DEPTH) * S + gtid, sl);
      buf = (buf == DEPTH - 1) ? 0 : buf + 1;
    }
    // epilogue: drain 6 -> 3 -> 0
    asm volatile("s_waitcnt vmcnt(6)" ::: "memory");
    __builtin_amdgcn_sched_barrier(0);
    proc_buf(&sbuf[buf][wv][0], ln, pc, nc, psum, h);
    buf = (buf == DEPTH - 1) ? 0 : buf + 1;
    asm volatile("s_waitcnt vmcnt(3)" ::: "memory");
    __builtin_amdgcn_sched_barrier(0);
    proc_buf(&sbuf[buf][wv][0], ln, pc, nc, psum, h);
    buf = (buf == DEPTH - 1) ? 0 : buf + 1;
    asm volatile("s_waitcnt vmcnt(0)" ::: "memory");
    __builtin_amdgcn_sched_barrier(0);
    proc_buf(&sbuf[buf][wv][0], ln, pc, nc, psum, h);
  }

  // remainder grid-stride float4 steps (direct loads)
  for (int i = PST * S + gtid; i < n4; i += S) {
    float4 pv = p4[i], gv = g4[i], mv = m4[i];
    proc1(pv.x, gv.x, mv.x, pc, nc, psum, h);
    proc1(pv.y, gv.y, mv.y, pc, nc, psum, h);
    proc1(pv.z, gv.z, mv.z, pc, nc, psum, h);
    proc1(pv.w, gv.w, mv.w, pc, nc, psum, h);
  }
  // scalar tail (n % 4 != 0)
  for (int t = n4 * 4 + gtid; t < n; t += S) {
    proc1(pred[t], gt[t], mask[t], pc, nc, psum, h);
  }

  // block reduce pc/nc/psum
  unsigned long long pcl = pc, ncl = nc;
  for (int off = 32; off > 0; off >>= 1) {
    pcl += __shfl_down(pcl, off);
    ncl += __shfl_down(ncl, off);
    psum += __shfl_down(psum, off);
  }
  __shared__ unsigned long long spc[4], snc[4];
  __shared__ double sps[4];
  if (ln == 0) { spc[wv] = pcl; snc[wv] = ncl; sps[wv] = psum; }
  __syncthreads();   // also ensures all LDS histogram atomics are complete
  if (threadIdx.x == 0) {
    unsigned long long tp = 0, tn = 0; double ts = 0.0;
    for (int w = 0; w < 4; w++) { tp += spc[w]; tn += snc[w]; ts += sps[w]; }
    atomicAdd(&ctrl->pos_cnt, tp);
    atomicAdd(&ctrl->neg_cnt, tn);
    unsafeAtomicAdd(&ctrl->pos_sum, ts);
  }
  // flush LDS histogram to global (skip empty bins)
  for (int b = threadIdx.x; b < NBINS1; b += blockDim.x) {
    unsigned c = h[b];
    if (c) atomicAdd(&hist1[b], c);
  }
}

// ---------- Kernel 5: select + midpoint neg_sum + output (1 block) ---------
extern "C" __global__ void __launch_bounds__(256)
k5_final(const unsigned* __restrict__ hist1, Ctrl* __restrict__ ctrl,
         float* __restrict__ out) {
  const int T = 256, CH = NBINS1 / T;  // 16 bins per thread
  __shared__ unsigned long long sarr[T];
  __shared__ unsigned long long sk;
  __shared__ unsigned sB, skrem;
  __shared__ double sred[4];
  int t = threadIdx.x;
  int wv = t >> 6, ln = t & 63;

  unsigned cnt[CH];
  unsigned long long tot = 0;
  for (int j = 0; j < CH; j++) { cnt[j] = hist1[t * CH + j]; tot += cnt[j]; }
  sarr[t] = tot;
  if (t == 0) {
    sB = 0xFFFFFFFFu; skrem = 0u;
    unsigned long long pos = ctrl->pos_cnt, negtot = ctrl->neg_cnt;
    unsigned long long k = 0;
    if (pos > 0) {               // FALLBACK_NEG=0 when pos==0
      k = pos * 3ull;            // floor(pos*3.0), exact in integer
      if (k > negtot) k = negtot;
    }
    ctrl->k = k;
    sk = k;
  }
  __syncthreads();
  // inclusive suffix scan: sarr[t] = sum over threads >= t
  for (int off = 1; off < T; off <<= 1) {
    unsigned long long v = (t + off < T) ? sarr[t + off] : 0ull;
    __syncthreads();
    sarr[t] += v;
    __syncthreads();
  }
  unsigned long long k = sk;
  if (k > 0) {
    unsigned long long above = sarr[t] - tot;
    if (above < k && sarr[t] >= k) {
      unsigned long long cum = above;
      for (int j = CH - 1; j >= 0; j--) {
        if (cum + (unsigned long long)cnt[j] >= k) {
          sB = (unsigned)(t * CH + j);
          skrem = (unsigned)(k - cum);
          break;
        }
        cum += cnt[j];
      }
    }
  }
  __syncthreads();
  unsigned B = sB;

  // neg_sum (midpoint model): each thread sums its own bins above B
  double s = 0.0;
  if (B != 0xFFFFFFFFu) {
    for (int j = 0; j < CH; j++) {
      unsigned bi = (unsigned)(t * CH + j);
      if (bi > B && cnt[j]) s += (double)cnt[j] * bin_mid(bi);
    }
  }
  for (int off = 32; off > 0; off >>= 1) s += __shfl_down(s, off);
  if (ln == 0) sred[wv] = s;
  __syncthreads();
  if (t == 0) {
    double neg_sum = sred[0] + sred[1] + sred[2] + sred[3];
    if (skrem > 0 && B != 0xFFFFFFFFu)
      neg_sum += (double)skrem * bin_mid(B);
    double denom = (double)ctrl->pos_cnt + (double)k + 1e-6;
    out[0] = (float)((ctrl->pos_sum + neg_sum) / denom);
  }
}

// ---------------------------------------------------------------------------
extern "C" void kernel_launch(void* const* d_in, const int* in_sizes, int n_in,
                              void* d_out, int out_size, void* d_ws, size_t ws_size,
                              hipStream_t stream) {
  const float* pred = (const float*)d_in[0];
  const float* gt   = (const float*)d_in[1];
  const float* mask = (const float*)d_in[2];
  float* out = (float*)d_out;
  int n = in_sizes[0];
  int n4 = n / 4;
  char* ws = (char*)d_ws;

  // layout: ctrl@0 (64B), hist1@256 (16KB) -> zero first 16640 bytes
  const size_t HIST1_OFF = 256;
  const size_t ZERO_BYTES = HIST1_OFF + NBINS1 * sizeof(unsigned);   // 16640

  Ctrl* ctrl = (Ctrl*)ws;
  unsigned* hist1 = (unsigned*)(ws + HIST1_OFF);

  hipMemsetAsync(d_ws, 0, ZERO_BYTES, stream);
  k1_hist<<<K1_BLOCKS, 256, 0, stream>>>(pred, gt, mask, hist1, ctrl, n4, n);
  k5_final<<<1, 256, 0, stream>>>(hist1, ctrl, out);
}